// Round 8
// baseline (254.972 us; speedup 1.0000x reference)
//
#include <hip/hip_runtime.h>
#include <math.h>

#define NN_   6000
#define EE_   192000
#define CIN_  32
#define CHID_ 64
#define KK_   125   // 5^3 spline kernel cells
#define EB_   32    // edge batch per block in build_T (= MFMA K)
#define CH1_  4     // x-GEMM outer chunks (each = CPB*64 cols)
#define CH2_  8     // h-GEMM outer chunks
#define CPB_  16    // k-chunks per GEMM block (64 cols each)
#define MTILE_ 128  // GEMM m-tile (4 waves x 2 row-frags x 16)

// fp32 -> bf16 round-to-nearest-even
static __device__ __forceinline__ unsigned short f2bf(float f) {
    unsigned int u = __builtin_bit_cast(unsigned int, f);
    u += 0x7fff + ((u >> 16) & 1);
    return (unsigned short)(u >> 16);
}
static __device__ __forceinline__ float bf2f(unsigned short h) {
    unsigned int u = ((unsigned int)h) << 16;
    return __builtin_bit_cast(float, u);
}

// counted vmcnt wait: waits own wave's outstanding VMEM <= N, leaving newer
// prefetch loads in flight. "memory" clobber stops load hoisting across it;
// sched_barrier(0) stops the machine scheduler (guide rule #18).
template<int N> static __device__ __forceinline__ void vwait() {
    asm volatile("s_waitcnt vmcnt(%0)" :: "n"(N) : "memory");
    __builtin_amdgcn_sched_barrier(0);
}

// ---------------------------------------------------------------------------
// Launch 1: deg count + weight packs (independent work, one launch).
// deg is PACKED again -- R7's 64B-strided counters were a net regression
// (bigger memset, uncoalesced scan reads outweighed any atomic relief).
// ---------------------------------------------------------------------------
#define PK1_ (192 * KK_ * CIN_)    // 768000
#define PK2_ (128 * KK_ * CHID_)   // 1024000
#define CB_  ((EE_ + 255) / 256)   // 750 count blocks
__global__ __launch_bounds__(256) void count_pack_kernel(
    const int* __restrict__ ei, int* __restrict__ deg,
    const float* __restrict__ W_xr, const float* __restrict__ W_xz,
    const float* __restrict__ W_xn, const float* __restrict__ W_hr,
    const float* __restrict__ W_hz,
    unsigned short* __restrict__ B1t, unsigned short* __restrict__ B2t)
{
    const int b = blockIdx.x;
    if (b < CB_) {
        int e = b * 256 + threadIdx.x;
        if (e < EE_) atomicAdd(&deg[ei[EE_ + e]], 1);
        return;
    }
    int gid = (b - CB_) * 256 + threadIdx.x;
    if (gid < PK1_) {
        int n  = gid / (KK_ * CIN_);
        int kk = gid % (KK_ * CIN_);
        int conv = n >> 6, o = n & 63;
        const float* W = (conv == 0) ? W_xr : ((conv == 1) ? W_xz : W_xn);
        B1t[gid] = f2bf(W[(size_t)kk * 64 + o]);
    } else if (gid < PK1_ + PK2_) {
        int g2 = gid - PK1_;
        int n  = g2 / (KK_ * CHID_);
        int kk = g2 % (KK_ * CHID_);
        int conv = n >> 6, o = n & 63;
        const float* W = (conv == 0) ? W_hr : W_hz;
        B2t[g2] = f2bf(W[(size_t)kk * 64 + o]);
    }
}

__global__ __launch_bounds__(1024) void scan_kernel(
    const int* __restrict__ deg, int* __restrict__ offs, int* __restrict__ cursor)
{
    __shared__ int part[1024];
    const int tid = threadIdx.x;
    const int CH = (NN_ + 1023) / 1024;   // 6
    const int base = tid * CH;
    int loc[CH];
    int s = 0;
#pragma unroll
    for (int i = 0; i < CH; ++i) {
        int v = (base + i < NN_) ? deg[base + i] : 0;
        loc[i] = s; s += v;
    }
    part[tid] = s;
    __syncthreads();
    for (int off = 1; off < 1024; off <<= 1) {
        int v = (tid >= off) ? part[tid - off] : 0;
        __syncthreads();
        part[tid] += v;
        __syncthreads();
    }
    const int pre = (tid > 0) ? part[tid - 1] : 0;
#pragma unroll
    for (int i = 0; i < CH; ++i) {
        if (base + i < NN_) {
            offs[base + i]   = pre + loc[i];
            cursor[base + i] = pre + loc[i];
        }
    }
    if (tid == 1023) offs[NN_] = part[1023];
}

// Compute per-edge spline meta ONCE, scattered to dst-sorted position.
__global__ __launch_bounds__(256) void prep_kernel(
    const int* __restrict__ ei, const float* __restrict__ attr,
    int* __restrict__ cursor, float4* __restrict__ meta_s, int* __restrict__ src_s)
{
    int e = blockIdx.x * 256 + threadIdx.x;
    if (e >= EE_) return;
    const int dst = ei[EE_ + e];
    const int p   = atomicAdd(&cursor[dst], 1);
    float f[3]; int i0[3];
#pragma unroll
    for (int d = 0; d < 3; ++d) {
        float u  = attr[e * 3 + d] * 4.0f;
        float fl = floorf(u);
        fl = fminf(fmaxf(fl, 0.0f), 3.0f);
        i0[d] = (int)fl;
        f[d]  = u - fl;
    }
    meta_s[p] = make_float4(f[0], f[1], f[2],
        __int_as_float(i0[0] * 25 + i0[1] * 5 + i0[2]));
    src_s[p] = ei[e];
}

// ---------------------------------------------------------------------------
// Per-node T build v8: dense-MFMA (R3-proven), now 512 threads / 8 waves.
// Each wave owns ONE 16-cell row-tile (halves per-wave MFMA work vs v7);
// M-scatter (threads 0-255, 8/edge) and fbT fill (threads 256-511, 8/edge)
// run IN PARALLEL; zero/output phases get 2x the threads. Same per-node
// accumulation order as v6/v7 -> identical numerics.
// ---------------------------------------------------------------------------
template<int C>
__global__ __launch_bounds__(512) void build_T_kernel(
    const float4* __restrict__ meta_s, const int* __restrict__ src_s,
    const float* __restrict__ feat, const int* __restrict__ offs,
    unsigned short* __restrict__ Tb)
{
    constexpr int MP  = 40;              // padded row stride (shorts)
    constexpr int CT  = C / 16;          // B col-tiles (4 or 2)
    constexpr int CPT = C / 8;           // channels per fbT-fill thread
    using bf16x8 = __attribute__((ext_vector_type(8))) short;
    using f32x4  = __attribute__((ext_vector_type(4))) float;

    __shared__ __align__(16) unsigned short Mt [128 * MP];  // [cell][edge] bf16
    __shared__ __align__(16) unsigned short fbT[C   * MP];  // [channel][edge] bf16
    __shared__ int   s_src[EB_];
    __shared__ int   s_cell[EB_];                           // base cell index
    __shared__ float s_basis[EB_ * 8];

    const int tid  = threadIdx.x;
    const int wave = tid >> 6;          // 0..7
    const int lane = tid & 63;
    const int quad = lane >> 4;
    const int l16  = lane & 15;
    const int node = blockIdx.x;

    // zero fbT once: stale LDS may be NaN-patterned; NaN*0 = NaN in MFMA
    for (int i = tid; i < C * MP / 8; i += 512)
        ((uint4*)fbT)[i] = make_uint4(0u, 0u, 0u, 0u);

    const int j0 = offs[node], j1 = offs[node + 1];

    f32x4 acc[CT];
#pragma unroll
    for (int ct = 0; ct < CT; ++ct) acc[ct] = (f32x4){0.f, 0.f, 0.f, 0.f};

    for (int jb = j0; jb < j1; jb += EB_) {
        const int m = min(EB_, j1 - jb);

        __syncthreads();   // prev batch MFMA reads done
        // re-zero M so stale cells / partial-batch columns contribute 0
        for (int i = tid; i < 128 * MP / 8; i += 512)
            ((uint4*)Mt)[i] = make_uint4(0u, 0u, 0u, 0u);
        if (tid < m) {
            const float4 mt = meta_s[jb + tid];
            s_src[tid]  = src_s[jb + tid];
            s_cell[tid] = __float_as_int(mt.w);
            const float f0 = mt.x, f1 = mt.y, f2 = mt.z;
            const float g0 = 1.f - f0, g1 = 1.f - f1, g2 = 1.f - f2;
            float4 blo = make_float4(g0*g1*g2, f0*g1*g2, g0*f1*g2, f0*f1*g2);
            float4 bhi = make_float4(g0*g1*f2, f0*g1*f2, g0*f1*f2, f0*f1*f2);
            *(float4*)&s_basis[tid * 8]     = blo;
            *(float4*)&s_basis[tid * 8 + 4] = bhi;
        }
        __syncthreads();

        if (tid < 256) {
            // M scatter: 8 threads/edge, one Mt entry each (race-free).
            // s-bit -> cell offset: b0->+25, b1->+5, b2->+1.
            const int e = tid >> 3, s = tid & 7;
            if (e < m) {
                const int cell = s_cell[e] + 25 * (s & 1)
                               + 5 * ((s >> 1) & 1) + ((s >> 2) & 1);
                Mt[cell * MP + e] = f2bf(s_basis[e * 8 + s]);
            }
        } else {
            // B = feat^T fill: 8 threads/edge, CPT channels each (parallel
            // with the scatter -- disjoint LDS regions)
            const int u = tid - 256;
            const int e = u >> 3, cg = (u & 7) * CPT;
            if (e < m) {
                const float* fr = &feat[(size_t)s_src[e] * C + cg];
#pragma unroll
                for (int c4 = 0; c4 < CPT; c4 += 4) {
                    float4 v = *(const float4*)(fr + c4);
                    fbT[(cg + c4 + 0) * MP + e] = f2bf(v.x);
                    fbT[(cg + c4 + 1) * MP + e] = f2bf(v.y);
                    fbT[(cg + c4 + 2) * MP + e] = f2bf(v.z);
                    fbT[(cg + c4 + 3) * MP + e] = f2bf(v.w);
                }
            }
        }
        __syncthreads();

        bf16x8 a = *(const bf16x8*)&Mt[(wave * 16 + l16) * MP + quad * 8];
#pragma unroll
        for (int ct = 0; ct < CT; ++ct) {
            bf16x8 b = *(const bf16x8*)&fbT[(ct * 16 + l16) * MP + quad * 8];
            acc[ct] = __builtin_amdgcn_mfma_f32_16x16x32_bf16(a, b, acc[ct], 0, 0, 0);
        }
    }

    unsigned short* To = Tb + (size_t)node * (KK_ * C);
    const int rbase = wave * 16 + quad * 4;
#pragma unroll
    for (int ct = 0; ct < CT; ++ct) {
#pragma unroll
        for (int r = 0; r < 4; ++r) {
            const int R = rbase + r;
            if (R < KK_) To[R * C + ct * 16 + l16] = f2bf(acc[ct][r]);
        }
    }
}

// ---------------------------------------------------------------------------
// GEMM body v12: true 2-blocks/CU. R7 post-mortem: 2x81920B = exactly
// 163840B did NOT co-schedule (occupancy pinned 9.4% = 1 block/CU) -- the
// TLP theory was never tested. v12: MTILE 128, RF 2 -> slot 32KB, arena
// 64KB/block -> 128KB for 2 blocks with 32KB slack. Same counted-vmcnt
// depth-1 protocol (R6-proven), LW = 8 (h) / 7 (x). If occupancy ~2x and
// MfmaUtil rises -> TLP confirmed; if occupancy rises but MfmaUtil stays
// ~17% -> stall is intra-wave, pivot. Numerics identical.
// ---------------------------------------------------------------------------
template<int NT, int NTF, int CPB, int LW>
static __device__ __forceinline__ void gemm_body(
    unsigned short* arena,
    const unsigned short* __restrict__ A, const unsigned short* __restrict__ Bt,
    const unsigned short* __restrict__ zp,
    unsigned short* __restrict__ P, int M, int Kd, int chunk, int zhalf)
{
    constexpr int COLS   = 64;
    constexpr int RF     = 2;
    constexpr int NFRAG  = NT / 16;
    constexpr int CSP    = NT + 8;
    constexpr int ASH    = MTILE_ * COLS;          // 8192 shorts
    constexpr int SLOT   = ASH + 128 * COLS;       // 16384 shorts (h-sized B)
    constexpr int AUNITS = MTILE_ * COLS / 8;      // 1024 (4 per thread)
    constexpr int BUNITS = NT * COLS / 8;          // 1024 / 768
    constexpr int NPASS  = MTILE_ / 64;            // 2 epilogue passes

    using bf16x8 = __attribute__((ext_vector_type(8))) short;
    using f32x4  = __attribute__((ext_vector_type(4))) float;

    const int tid  = threadIdx.x;
    const int wave = tid >> 6;
    const int lane = tid & 63;
    const int quad = lane >> 4;
    const int l16  = lane & 15;
    const int m0   = blockIdx.x * MTILE_;
    const unsigned short* Bp = Bt + (size_t)zhalf * NT * Kd;
    const int kbase = chunk * CPB * COLS;
    const int ccmax = min(CPB, (Kd - kbase + COLS - 1) / COLS);

    f32x4 acc[RF][NFRAG];
#pragma unroll
    for (int t = 0; t < RF; ++t)
#pragma unroll
        for (int f = 0; f < NFRAG; ++f) acc[t][f] = (f32x4){0.f, 0.f, 0.f, 0.f};

    // LDS[row][b] = global blk (b ^ (row&7)); readers apply the same XOR.
    // K-tail A-blocks load 16B of zeros from zp so every wave issues exactly
    // LW VMEM ops per STAGE (keeps the vmcnt arithmetic exact). OOB M-rows
    // read adjacent mapped workspace (finite bf16; never stored).
    auto STAGE = [&](int cc, int slot) {
        unsigned short* Abuf = arena + slot * SLOT;
        unsigned short* Bbuf = Abuf + ASH;
        const int k0 = kbase + cc * COLS;
#pragma unroll
        for (int i = 0; i < AUNITS / 256; ++i) {
            const int u    = tid + i * 256;
            const int row  = u >> 3;
            const int gblk = (u & 7) ^ (row & 7);
            const int k    = k0 + gblk * 8;
            const unsigned short* g = (k + 8 <= Kd)
                ? A + (size_t)(m0 + row) * Kd + k
                : zp + (u & 3) * 8;
            __builtin_amdgcn_global_load_lds(
                (const __attribute__((address_space(1))) void*)g,
                (__attribute__((address_space(3))) void*)(Abuf + u * 8),
                16, 0, 0);
        }
#pragma unroll
        for (int i = 0; i < BUNITS / 256; ++i) {
            const int u    = tid + i * 256;
            const int row  = u >> 3;
            const int gblk = (u & 7) ^ (row & 7);
            const unsigned short* g = Bp + (size_t)row * Kd + k0 + gblk * 8;
            __builtin_amdgcn_global_load_lds(
                (const __attribute__((address_space(1))) void*)g,
                (__attribute__((address_space(3))) void*)(Bbuf + u * 8),
                16, 0, 0);
        }
    };

    STAGE(0, 0);

    for (int cc = 0; cc < ccmax; ++cc) {
        // slot (cc+1)&1 was last read at MFMA(cc-1); trailing barrier of
        // iteration cc-1 makes the overwrite safe here.
        if (cc + 1 < ccmax) { STAGE(cc + 1, (cc + 1) & 1); vwait<LW>(); }
        else                { vwait<0>(); }
        __builtin_amdgcn_s_barrier();            // all waves: tile cc landed
        asm volatile("" ::: "memory");

        const unsigned short* Ac = arena + (cc & 1) * SLOT;
        const unsigned short* Bc = Ac + ASH;
        __builtin_amdgcn_s_setprio(1);
#pragma unroll
        for (int s = 0; s < 2; ++s) {
            bf16x8 av[RF];
#pragma unroll
            for (int t = 0; t < RF; ++t) {
                const int row = (wave * RF + t) * 16 + l16;
                av[t] = *(const bf16x8*)
                    &Ac[row * COLS + (((s * 4 + quad) ^ (l16 & 7)) * 8)];
            }
#pragma unroll
            for (int f = 0; f < NFRAG; ++f) {
                bf16x8 bv = *(const bf16x8*)
                    &Bc[(f * 16 + l16) * COLS + (((s * 4 + quad) ^ (l16 & 7)) * 8)];
#pragma unroll
                for (int t = 0; t < RF; ++t)
                    acc[t][f] = __builtin_amdgcn_mfma_f32_16x16x32_bf16(
                        av[t], bv, acc[t][f], 0, 0, 0);
            }
        }
        __builtin_amdgcn_s_setprio(0);
        asm volatile("" ::: "memory");
        __builtin_amdgcn_s_barrier();            // all waves done reading slot
        asm volatile("" ::: "memory");
    }

    // epilogue: NPASS chunked transpose passes of 64 rows through the arena
    unsigned short* Cs = arena;   // [64][CSP]
    unsigned short* Pc = P + ((size_t)chunk * M + m0) * NTF + zhalf * NT;
#pragma unroll
    for (int p = 0; p < NPASS; ++p) {
        __syncthreads();
#pragma unroll
        for (int t = 0; t < RF; ++t) {
            const int fr = wave * RF + t;
            if ((fr >> 2) == p) {
                const int rb = (fr & 3) * 16 + quad * 4;
#pragma unroll
                for (int f = 0; f < NFRAG; ++f) {
                    const int col = f * 16 + l16;
#pragma unroll
                    for (int r = 0; r < 4; ++r)
                        Cs[(rb + r) * CSP + col] = f2bf(acc[t][f][r]);
                }
            }
        }
        __syncthreads();
        constexpr int UNITS = 64 * NT / 8;
        for (int u = tid; u < UNITS; u += 256) {
            const int row = (u * 8) / NT, col = (u * 8) % NT;
            if (m0 + p * 64 + row < M)
                *(uint4*)&Pc[(size_t)(p * 64 + row) * NTF + col] =
                    *(const uint4*)&Cs[row * CSP + col];
        }
    }
}

// Merged GEMM: blockIdx.y < CH2_ -> h-chunk; else x-(chunk,half).
__global__ __launch_bounds__(256) void gemm_all_kernel(
    const unsigned short* __restrict__ Tx, const unsigned short* __restrict__ B1t,
    unsigned short* __restrict__ P1,
    const unsigned short* __restrict__ Th, const unsigned short* __restrict__ B2t,
    unsigned short* __restrict__ P2, const unsigned short* __restrict__ zp)
{
    // 2 slots x (A 16384B + B 16384B) = 65536 B -> 2 blocks/CU w/ 32KB slack
    __shared__ __align__(16) unsigned short arena[2 * 16384];
    const int y = blockIdx.y;
    if (y < CH2_) {
        gemm_body<128, 128, CPB_, 8>(arena, Th, B2t, zp, P2, NN_, KK_ * CHID_, y, 0);
    } else {
        const int g = y - CH2_;            // 0..7 -> (chunk 0..3, half 0..1)
        gemm_body<96, 192, CPB_, 7>(arena, Tx, B1t, zp, P1, NN_, KK_ * CIN_, g >> 1, g & 1);
    }
}

// ---------------------------------------------------------------------------
// Epilogue: one wave per node, lane = output channel. Sums bf16 split-K
// partials (L2-resident), mean-agg, root GEMV, GRU gates.
// ---------------------------------------------------------------------------
__global__ __launch_bounds__(256) void epilogue_kernel(
    const unsigned short* __restrict__ P1, const unsigned short* __restrict__ P2,
    const int* __restrict__ offs,
    const float* __restrict__ x, const float* __restrict__ hidden,
    const float* __restrict__ root_xr, const float* __restrict__ root_hr,
    const float* __restrict__ root_xz, const float* __restrict__ root_hz,
    const float* __restrict__ root_xn,
    const float* __restrict__ b_xr, const float* __restrict__ b_hr,
    const float* __restrict__ b_xz, const float* __restrict__ b_hz,
    const float* __restrict__ b_xn,
    float* __restrict__ out)
{
    __shared__ float xsh[4][32];
    __shared__ float hsh[4][64];
    const int w = threadIdx.x >> 6;
    const int o = threadIdx.x & 63;
    const int m = blockIdx.x * 4 + w;
    if (m >= NN_) return;

    if (o < 32) xsh[w][o] = x[(size_t)m * 32 + o];
    const float hval = hidden[(size_t)m * 64 + o];
    hsh[w][o] = hval;

    float axr = 0.f, axz = 0.f, axn = 0.f;
#pragma unroll
    for (int c = 0; c < CH1_; ++c) {
        const unsigned short* p = P1 + ((size_t)c * NN_ + m) * 192;
        axr += bf2f(p[o]); axz += bf2f(p[64 + o]); axn += bf2f(p[128 + o]);
    }
    float ahr = 0.f, ahz = 0.f;
#pragma unroll
    for (int c = 0; c < CH2_; ++c) {
        const unsigned short* p = P2 + ((size_t)c * NN_ + m) * 128;
        ahr += bf2f(p[o]); ahz += bf2f(p[64 + o]);
    }

    const int   dg   = offs[m + 1] - offs[m];
    const float dinv = 1.0f / fmaxf((float)dg, 1.0f);
    axr *= dinv; axz *= dinv; axn *= dinv; ahr *= dinv; ahz *= dinv;

    float sxr = 0.f, sxz = 0.f, sxn = 0.f;
#pragma unroll
    for (int c = 0; c < CIN_; ++c) {
        float xv = xsh[w][c];
        sxr += xv * root_xr[c * 64 + o];
        sxz += xv * root_xz[c * 64 + o];
        sxn += xv * root_xn[c * 64 + o];
    }
    float shr = 0.f, shz = 0.f;
#pragma unroll
    for (int c = 0; c < CHID_; ++c) {
        float hv = hsh[w][c];
        shr += hv * root_hr[c * 64 + o];
        shz += hv * root_hz[c * 64 + o];
    }

    const float conv_xr = axr + sxr + b_xr[o];
    const float conv_xz = axz + sxz + b_xz[o];
    const float conv_xn = axn + sxn + b_xn[o];
    const float hr_out  = ahr + shr + b_hr[o];
    const float conv_hz = ahz + shz + b_hz[o];

    const float rg = 1.0f / (1.0f + expf(-(conv_xr + hr_out)));
    const float zg = 1.0f / (1.0f + expf(-(conv_xz + conv_hz)));
    const float ng = tanhf(conv_xn + rg * hr_out);
    out[(size_t)m * 64 + o] = (1.0f - zg) * ng + zg * hval;
}

// ---------------------------------------------------------------------------
extern "C" void kernel_launch(void* const* d_in, const int* in_sizes, int n_in,
                              void* d_out, int out_size, void* d_ws, size_t ws_size,
                              hipStream_t stream)
{
    const float* x       = (const float*)d_in[0];
    const float* hidden  = (const float*)d_in[1];
    const int*   ei      = (const int*)  d_in[2];
    const float* attr    = (const float*)d_in[3];
    const float* W_xr    = (const float*)d_in[4];
    const float* root_xr = (const float*)d_in[5];
    const float* b_xr    = (const float*)d_in[6];
    const float* W_hr    = (const float*)d_in[7];
    const float* root_hr = (const float*)d_in[8];
    const float* b_hr    = (const float*)d_in[9];
    const float* W_xz    = (const float*)d_in[10];
    const float* root_xz = (const float*)d_in[11];
    const float* b_xz    = (const float*)d_in[12];
    const float* W_hz    = (const float*)d_in[13];
    const float* root_hz = (const float*)d_in[14];
    const float* b_hz    = (const float*)d_in[15];
    const float* W_xn    = (const float*)d_in[16];
    const float* root_xn = (const float*)d_in[17];
    const float* b_xn    = (const float*)d_in[18];
    // d_in[19..21] (W_hn/root_hn/b_hn) are dead: reference reuses hr_out.
    float* out = (float*)d_out;

    // Workspace (~175 MB). No aliasing (gemm-x reads Tx while gemm-h writes
    // P2 concurrently inside gemm_all). A/B staging may read a few rows past
    // a region's end -- all land in adjacent mapped workspace (finite bf16);
    // A K-tail loads zeros from zpad so those products are exactly 0.
    char* w = (char*)d_ws;
    unsigned short* Tx  = (unsigned short*)w; w += (size_t)NN_ * KK_ * CIN_  * 2;  // 48 MB
    unsigned short* Th  = (unsigned short*)w; w += (size_t)NN_ * KK_ * CHID_ * 2;  // 96 MB
    unsigned short* B1t = (unsigned short*)w; w += (size_t)192 * KK_ * CIN_  * 2;  // 1.5 MB
    unsigned short* B2t = (unsigned short*)w; w += (size_t)128 * KK_ * CHID_ * 2;  // 2.0 MB
    unsigned short* P1  = (unsigned short*)w; w += (size_t)CH1_ * NN_ * 192 * 2;   // 9.2 MB
    unsigned short* P2  = (unsigned short*)w; w += (size_t)CH2_ * NN_ * 128 * 2;   // 12.3 MB
    float4* meta_s = (float4*)w; w += (size_t)EE_ * 16;                            // 3.07 MB
    int* src_s  = (int*)w;   w += (size_t)EE_ * 4;                                 // 0.77 MB
    int* deg    = (int*)w;   w += (size_t)NN_ * 4;
    int* offs   = (int*)w;   w += (size_t)(NN_ + 4) * 4;
    int* cursor = (int*)w;   w += (size_t)NN_ * 4;
    unsigned short* zpad = (unsigned short*)w; w += 256;                           // zeroed

    const int MT = (NN_ + MTILE_ - 1) / MTILE_;   // 47 m-tiles

    hipMemsetAsync(deg, 0, (size_t)NN_ * 4, stream);
    hipMemsetAsync(zpad, 0, 256, stream);

    // ---- launch 1: deg count + weight packs (independent, merged) ----
    const int PACKB = (PK1_ + PK2_ + 255) / 256;
    count_pack_kernel<<<CB_ + PACKB, 256, 0, stream>>>(
        ei, deg, W_xr, W_xz, W_xn, W_hr, W_hz, B1t, B2t);

    // ---- scan + sorted edge records ----
    scan_kernel<<<1, 1024, 0, stream>>>(deg, offs, cursor);
    prep_kernel<<<(EE_ + 255) / 256, 256, 0, stream>>>(ei, attr, cursor, meta_s, src_s);

    // ---- T builds: MFMA formulation, 8 waves/block ----
    build_T_kernel<CHID_><<<NN_, 512, 0, stream>>>(meta_s, src_s, hidden, offs, Th);
    build_T_kernel<CIN_><<<NN_, 512, 0, stream>>>(meta_s, src_s, x, offs, Tx);

    // ---- merged x+h GEMMs (co-resident, one launch) ----
    gemm_all_kernel<<<dim3(MT, CH2_ + 2 * CH1_), 256, 0, stream>>>(
        Tx, B1t, P1, Th, B2t, P2, zpad);

    // ---- fused reduce + GRU epilogue (wave per node) ----
    epilogue_kernel<<<(NN_ + 3) / 4, 256, 0, stream>>>(
        P1, P2, offs, x, hidden,
        root_xr, root_hr, root_xz, root_hz, root_xn,
        b_xr, b_hr, b_xz, b_hz, b_xn, out);
}

// Round 9
// 241.697 us; speedup vs baseline: 1.0549x; 1.0549x over previous
//
#include <hip/hip_runtime.h>
#include <math.h>

#define NN_   6000
#define EE_   192000
#define CIN_  32
#define CHID_ 64
#define KK_   125   // 5^3 spline kernel cells
#define EB_   32    // edge batch per block in build_T (= MFMA K)
#define CH1_  4     // x-GEMM outer chunks (each = CPB*64 cols)
#define CH2_  8     // h-GEMM outer chunks
#define CPB_  16    // k-chunks per GEMM block (64 cols each)
#define MTILE_ 128  // GEMM m-tile (4 waves x 2 row-frags x 16)

// fp32 -> bf16 round-to-nearest-even
static __device__ __forceinline__ unsigned short f2bf(float f) {
    unsigned int u = __builtin_bit_cast(unsigned int, f);
    u += 0x7fff + ((u >> 16) & 1);
    return (unsigned short)(u >> 16);
}
static __device__ __forceinline__ float bf2f(unsigned short h) {
    unsigned int u = ((unsigned int)h) << 16;
    return __builtin_bit_cast(float, u);
}

// counted vmcnt wait: waits own wave's outstanding VMEM <= N, leaving newer
// prefetch loads in flight. "memory" clobber stops load hoisting across it;
// sched_barrier(0) stops the machine scheduler (guide rule #18).
template<int N> static __device__ __forceinline__ void vwait() {
    asm volatile("s_waitcnt vmcnt(%0)" :: "n"(N) : "memory");
    __builtin_amdgcn_sched_barrier(0);
}

// ---------------------------------------------------------------------------
// Launch 1: deg count + weight packs.
// R9: pack is now a 64x64 LDS tile TRANSPOSE. The old per-element pack read
// W[kk*64+o] with consecutive threads stepping kk -> stride-256B reads, 64
// lines/wave, ~16x overfetch (~100+ MB of line traffic on 7.2 MB of W).
// Now: coalesced float4 row reads -> padded LDS tile -> coalesced bf16x8
// row writes of the transposed tile. Output bit-identical to the old pack.
// ---------------------------------------------------------------------------
#define RX_  (KK_ * CIN_)          // 4000 rows per x-conv weight
#define RH_  (KK_ * CHID_)         // 8000 rows per h-conv weight
#define NB1_ ((RX_ + 63) / 64)     // 63 tiles per x-conv (tail 32 rows)
#define NB2_ (RH_ / 64)            // 125 tiles per h-conv (exact)
#define PACKB_ (3 * NB1_ + 2 * NB2_)   // 439 pack blocks
#define CB_  ((EE_ + 255) / 256)   // 750 count blocks
__global__ __launch_bounds__(256) void count_pack_kernel(
    const int* __restrict__ ei, int* __restrict__ deg,
    const float* __restrict__ W_xr, const float* __restrict__ W_xz,
    const float* __restrict__ W_xn, const float* __restrict__ W_hr,
    const float* __restrict__ W_hz,
    unsigned short* __restrict__ B1t, unsigned short* __restrict__ B2t)
{
    __shared__ float ts[64][65];    // padded transpose tile
    const int b = blockIdx.x;
    const int tid = threadIdx.x;
    if (b < CB_) {
        int e = b * 256 + tid;
        if (e < EE_) atomicAdd(&deg[ei[EE_ + e]], 1);
        return;
    }
    const int pid = b - CB_;
    const float* W;
    unsigned short* Bo;
    int r0, Rv, RL;                 // tile row base, rows valid, row length
    if (pid < 3 * NB1_) {
        const int conv = pid / NB1_, rb = pid % NB1_;
        W  = (conv == 0) ? W_xr : ((conv == 1) ? W_xz : W_xn);
        Bo = B1t + (size_t)(conv * 64) * RX_;
        r0 = rb * 64; Rv = min(64, RX_ - r0); RL = RX_;
    } else {
        const int p2 = pid - 3 * NB1_;
        const int conv = p2 / NB2_, rb = p2 % NB2_;
        W  = (conv == 0) ? W_hr : W_hz;
        Bo = B2t + (size_t)(conv * 64) * RH_;
        r0 = rb * 64; Rv = 64; RL = RH_;
    }
    // load Rv x 64 floats, coalesced (16 float4 per row)
    for (int u = tid; u < Rv * 16; u += 256) {
        const int row = u >> 4, c4 = u & 15;
        float4 v = ((const float4*)(W + (size_t)(r0 + row) * 64))[c4];
        ts[row][c4 * 4 + 0] = v.x; ts[row][c4 * 4 + 1] = v.y;
        ts[row][c4 * 4 + 2] = v.z; ts[row][c4 * 4 + 3] = v.w;
    }
    __syncthreads();
    // write transposed: row o (0..63), cols r0..r0+Rv as packed bf16 pairs
    const int G = Rv >> 3;          // 8-element groups per output row
    for (int u = tid; u < 64 * G; u += 256) {
        const int o = u / G, g = u % G;
        unsigned int w4[4];
#pragma unroll
        for (int j = 0; j < 4; ++j) {
            unsigned int lo = f2bf(ts[g * 8 + 2 * j][o]);
            unsigned int hi = f2bf(ts[g * 8 + 2 * j + 1][o]);
            w4[j] = lo | (hi << 16);
        }
        *(uint4*)&Bo[(size_t)o * RL + r0 + g * 8] =
            make_uint4(w4[0], w4[1], w4[2], w4[3]);
    }
}

__global__ __launch_bounds__(1024) void scan_kernel(
    const int* __restrict__ deg, int* __restrict__ offs, int* __restrict__ cursor)
{
    __shared__ int part[1024];
    const int tid = threadIdx.x;
    const int CH = (NN_ + 1023) / 1024;   // 6
    const int base = tid * CH;
    int loc[CH];
    int s = 0;
#pragma unroll
    for (int i = 0; i < CH; ++i) {
        int v = (base + i < NN_) ? deg[base + i] : 0;
        loc[i] = s; s += v;
    }
    part[tid] = s;
    __syncthreads();
    for (int off = 1; off < 1024; off <<= 1) {
        int v = (tid >= off) ? part[tid - off] : 0;
        __syncthreads();
        part[tid] += v;
        __syncthreads();
    }
    const int pre = (tid > 0) ? part[tid - 1] : 0;
#pragma unroll
    for (int i = 0; i < CH; ++i) {
        if (base + i < NN_) {
            offs[base + i]   = pre + loc[i];
            cursor[base + i] = pre + loc[i];
        }
    }
    if (tid == 1023) offs[NN_] = part[1023];
}

// Compute per-edge spline meta ONCE, scattered to dst-sorted position.
__global__ __launch_bounds__(256) void prep_kernel(
    const int* __restrict__ ei, const float* __restrict__ attr,
    int* __restrict__ cursor, float4* __restrict__ meta_s, int* __restrict__ src_s)
{
    int e = blockIdx.x * 256 + threadIdx.x;
    if (e >= EE_) return;
    const int dst = ei[EE_ + e];
    const int p   = atomicAdd(&cursor[dst], 1);
    float f[3]; int i0[3];
#pragma unroll
    for (int d = 0; d < 3; ++d) {
        float u  = attr[e * 3 + d] * 4.0f;
        float fl = floorf(u);
        fl = fminf(fmaxf(fl, 0.0f), 3.0f);
        i0[d] = (int)fl;
        f[d]  = u - fl;
    }
    meta_s[p] = make_float4(f[0], f[1], f[2],
        __int_as_float(i0[0] * 25 + i0[1] * 5 + i0[2]));
    src_s[p] = ei[e];
}

// ---------------------------------------------------------------------------
// Per-node T build v6 (R3/R6-proven, REVERTED from v7/v8): dense-MFMA,
// 256 threads. R8 post-mortem: v7 parallel scatter (-5us) and v8 512-thread
// split (-5us) were both regressions -- basis in registers + thread-per-edge
// serial scatter + 4-wave barriers was the best measured form (R6: 245.2us
// total). Numerics identical across v6/v7/v8.
// ---------------------------------------------------------------------------
template<int C>
__global__ __launch_bounds__(256) void build_T_kernel(
    const float4* __restrict__ meta_s, const int* __restrict__ src_s,
    const float* __restrict__ feat, const int* __restrict__ offs,
    unsigned short* __restrict__ Tb)
{
    constexpr int MP  = 40;              // padded row stride (shorts)
    constexpr int CT  = C / 16;          // B col-tiles (4 or 2)
    constexpr int CPT = C / 8;           // channels per fbT-fill thread
    using bf16x8 = __attribute__((ext_vector_type(8))) short;
    using f32x4  = __attribute__((ext_vector_type(4))) float;

    __shared__ __align__(16) unsigned short Mt [128 * MP];  // [cell][edge] bf16
    __shared__ __align__(16) unsigned short fbT[C   * MP];  // [channel][edge] bf16
    __shared__ int s_src[EB_];

    const int tid  = threadIdx.x;
    const int wave = tid >> 6;
    const int lane = tid & 63;
    const int quad = lane >> 4;
    const int l16  = lane & 15;
    const int node = blockIdx.x;

    // zero fbT once: stale LDS may be NaN-patterned; NaN*0 = NaN in MFMA
    for (int i = tid; i < C * MP / 8; i += 256)
        ((uint4*)fbT)[i] = make_uint4(0u, 0u, 0u, 0u);

    const int j0 = offs[node], j1 = offs[node + 1];

    f32x4 acc[2][CT];
#pragma unroll
    for (int t = 0; t < 2; ++t)
#pragma unroll
        for (int ct = 0; ct < CT; ++ct) acc[t][ct] = (f32x4){0.f, 0.f, 0.f, 0.f};

    for (int jb = j0; jb < j1; jb += EB_) {
        const int m = min(EB_, j1 - jb);

        __syncthreads();   // prev batch MFMA reads done
        for (int i = tid; i < 128 * MP / 8; i += 256)
            ((uint4*)Mt)[i] = make_uint4(0u, 0u, 0u, 0u);
        if (tid < m) s_src[tid] = src_s[jb + tid];
        __syncthreads();

        // build M: thread-per-edge, 8 distinct rows of own column (race-free)
        if (tid < m) {
            const float4 mt = meta_s[jb + tid];
            const int base = __float_as_int(mt.w);
            const float f0 = mt.x, f1 = mt.y, f2 = mt.z;
            const float g0 = 1.f - f0, g1 = 1.f - f1, g2 = 1.f - f2;
            const float bb[8] = {g0*g1*g2, f0*g1*g2, g0*f1*g2, f0*f1*g2,
                                 g0*g1*f2, f0*g1*f2, g0*f1*f2, f0*f1*f2};
            const int oc[8] = {0, 25, 5, 30, 1, 26, 6, 31};
#pragma unroll
            for (int s = 0; s < 8; ++s)
                Mt[(base + oc[s]) * MP + tid] = f2bf(bb[s]);
        }
        // build B = feat^T: 8 threads per edge, CPT channels each
        {
            const int e = tid >> 3, cg = (tid & 7) * CPT;
            if (e < m) {
                const float* fr = &feat[(size_t)s_src[e] * C + cg];
#pragma unroll
                for (int c4 = 0; c4 < CPT; c4 += 4) {
                    float4 v = *(const float4*)(fr + c4);
                    fbT[(cg + c4 + 0) * MP + e] = f2bf(v.x);
                    fbT[(cg + c4 + 1) * MP + e] = f2bf(v.y);
                    fbT[(cg + c4 + 2) * MP + e] = f2bf(v.z);
                    fbT[(cg + c4 + 3) * MP + e] = f2bf(v.w);
                }
            }
        }
        __syncthreads();

        bf16x8 a0 = *(const bf16x8*)&Mt[((wave * 2 + 0) * 16 + l16) * MP + quad * 8];
        bf16x8 a1 = *(const bf16x8*)&Mt[((wave * 2 + 1) * 16 + l16) * MP + quad * 8];
#pragma unroll
        for (int ct = 0; ct < CT; ++ct) {
            bf16x8 b = *(const bf16x8*)&fbT[(ct * 16 + l16) * MP + quad * 8];
            acc[0][ct] = __builtin_amdgcn_mfma_f32_16x16x32_bf16(a0, b, acc[0][ct], 0, 0, 0);
            acc[1][ct] = __builtin_amdgcn_mfma_f32_16x16x32_bf16(a1, b, acc[1][ct], 0, 0, 0);
        }
    }

    unsigned short* To = Tb + (size_t)node * (KK_ * C);
#pragma unroll
    for (int t = 0; t < 2; ++t) {
        const int rbase = (wave * 2 + t) * 16 + quad * 4;
#pragma unroll
        for (int ct = 0; ct < CT; ++ct) {
#pragma unroll
            for (int r = 0; r < 4; ++r) {
                const int R = rbase + r;
                if (R < KK_) To[R * C + ct * 16 + l16] = f2bf(acc[t][ct][r]);
            }
        }
    }
}

// ---------------------------------------------------------------------------
// GEMM body v12 (R8, kept): depth-1 counted vmcnt, 64KB arena, 2 blocks/CU.
// R8 verdict: occupancy 9.4->13.8% but MfmaUtil ~18% and dur ~46us -- the
// gemm sits at its delivered L2-miss-BW floor (~2.4-2.9 TB/s with ~32KB
// A-miss bytes in flight/CU, invariant across R6/R8 schedules). Further
// schedule tuning is non-productive; left as best-measured.
// ---------------------------------------------------------------------------
template<int NT, int NTF, int CPB, int LW>
static __device__ __forceinline__ void gemm_body(
    unsigned short* arena,
    const unsigned short* __restrict__ A, const unsigned short* __restrict__ Bt,
    const unsigned short* __restrict__ zp,
    unsigned short* __restrict__ P, int M, int Kd, int chunk, int zhalf)
{
    constexpr int COLS   = 64;
    constexpr int RF     = 2;
    constexpr int NFRAG  = NT / 16;
    constexpr int CSP    = NT + 8;
    constexpr int ASH    = MTILE_ * COLS;          // 8192 shorts
    constexpr int SLOT   = ASH + 128 * COLS;       // 16384 shorts (h-sized B)
    constexpr int AUNITS = MTILE_ * COLS / 8;      // 1024 (4 per thread)
    constexpr int BUNITS = NT * COLS / 8;          // 1024 / 768
    constexpr int NPASS  = MTILE_ / 64;            // 2 epilogue passes

    using bf16x8 = __attribute__((ext_vector_type(8))) short;
    using f32x4  = __attribute__((ext_vector_type(4))) float;

    const int tid  = threadIdx.x;
    const int wave = tid >> 6;
    const int lane = tid & 63;
    const int quad = lane >> 4;
    const int l16  = lane & 15;
    const int m0   = blockIdx.x * MTILE_;
    const unsigned short* Bp = Bt + (size_t)zhalf * NT * Kd;
    const int kbase = chunk * CPB * COLS;
    const int ccmax = min(CPB, (Kd - kbase + COLS - 1) / COLS);

    f32x4 acc[RF][NFRAG];
#pragma unroll
    for (int t = 0; t < RF; ++t)
#pragma unroll
        for (int f = 0; f < NFRAG; ++f) acc[t][f] = (f32x4){0.f, 0.f, 0.f, 0.f};

    // LDS[row][b] = global blk (b ^ (row&7)); readers apply the same XOR.
    // K-tail A-blocks load 16B of zeros from zp so every wave issues exactly
    // LW VMEM ops per STAGE. OOB M-rows read adjacent mapped workspace.
    auto STAGE = [&](int cc, int slot) {
        unsigned short* Abuf = arena + slot * SLOT;
        unsigned short* Bbuf = Abuf + ASH;
        const int k0 = kbase + cc * COLS;
#pragma unroll
        for (int i = 0; i < AUNITS / 256; ++i) {
            const int u    = tid + i * 256;
            const int row  = u >> 3;
            const int gblk = (u & 7) ^ (row & 7);
            const int k    = k0 + gblk * 8;
            const unsigned short* g = (k + 8 <= Kd)
                ? A + (size_t)(m0 + row) * Kd + k
                : zp + (u & 3) * 8;
            __builtin_amdgcn_global_load_lds(
                (const __attribute__((address_space(1))) void*)g,
                (__attribute__((address_space(3))) void*)(Abuf + u * 8),
                16, 0, 0);
        }
#pragma unroll
        for (int i = 0; i < BUNITS / 256; ++i) {
            const int u    = tid + i * 256;
            const int row  = u >> 3;
            const int gblk = (u & 7) ^ (row & 7);
            const unsigned short* g = Bp + (size_t)row * Kd + k0 + gblk * 8;
            __builtin_amdgcn_global_load_lds(
                (const __attribute__((address_space(1))) void*)g,
                (__attribute__((address_space(3))) void*)(Bbuf + u * 8),
                16, 0, 0);
        }
    };

    STAGE(0, 0);

    for (int cc = 0; cc < ccmax; ++cc) {
        if (cc + 1 < ccmax) { STAGE(cc + 1, (cc + 1) & 1); vwait<LW>(); }
        else                { vwait<0>(); }
        __builtin_amdgcn_s_barrier();            // all waves: tile cc landed
        asm volatile("" ::: "memory");

        const unsigned short* Ac = arena + (cc & 1) * SLOT;
        const unsigned short* Bc = Ac + ASH;
        __builtin_amdgcn_s_setprio(1);
#pragma unroll
        for (int s = 0; s < 2; ++s) {
            bf16x8 av[RF];
#pragma unroll
            for (int t = 0; t < RF; ++t) {
                const int row = (wave * RF + t) * 16 + l16;
                av[t] = *(const bf16x8*)
                    &Ac[row * COLS + (((s * 4 + quad) ^ (l16 & 7)) * 8)];
            }
#pragma unroll
            for (int f = 0; f < NFRAG; ++f) {
                bf16x8 bv = *(const bf16x8*)
                    &Bc[(f * 16 + l16) * COLS + (((s * 4 + quad) ^ (l16 & 7)) * 8)];
#pragma unroll
                for (int t = 0; t < RF; ++t)
                    acc[t][f] = __builtin_amdgcn_mfma_f32_16x16x32_bf16(
                        av[t], bv, acc[t][f], 0, 0, 0);
            }
        }
        __builtin_amdgcn_s_setprio(0);
        asm volatile("" ::: "memory");
        __builtin_amdgcn_s_barrier();            // all waves done reading slot
        asm volatile("" ::: "memory");
    }

    // epilogue: NPASS chunked transpose passes of 64 rows through the arena
    unsigned short* Cs = arena;   // [64][CSP]
    unsigned short* Pc = P + ((size_t)chunk * M + m0) * NTF + zhalf * NT;
#pragma unroll
    for (int p = 0; p < NPASS; ++p) {
        __syncthreads();
#pragma unroll
        for (int t = 0; t < RF; ++t) {
            const int fr = wave * RF + t;
            if ((fr >> 2) == p) {
                const int rb = (fr & 3) * 16 + quad * 4;
#pragma unroll
                for (int f = 0; f < NFRAG; ++f) {
                    const int col = f * 16 + l16;
#pragma unroll
                    for (int r = 0; r < 4; ++r)
                        Cs[(rb + r) * CSP + col] = f2bf(acc[t][f][r]);
                }
            }
        }
        __syncthreads();
        constexpr int UNITS = 64 * NT / 8;
        for (int u = tid; u < UNITS; u += 256) {
            const int row = (u * 8) / NT, col = (u * 8) % NT;
            if (m0 + p * 64 + row < M)
                *(uint4*)&Pc[(size_t)(p * 64 + row) * NTF + col] =
                    *(const uint4*)&Cs[row * CSP + col];
        }
    }
}

// Merged GEMM: blockIdx.y < CH2_ -> h-chunk; else x-(chunk,half).
__global__ __launch_bounds__(256) void gemm_all_kernel(
    const unsigned short* __restrict__ Tx, const unsigned short* __restrict__ B1t,
    unsigned short* __restrict__ P1,
    const unsigned short* __restrict__ Th, const unsigned short* __restrict__ B2t,
    unsigned short* __restrict__ P2, const unsigned short* __restrict__ zp)
{
    // 2 slots x (A 16384B + B 16384B) = 65536 B -> 2 blocks/CU w/ 32KB slack
    __shared__ __align__(16) unsigned short arena[2 * 16384];
    const int y = blockIdx.y;
    if (y < CH2_) {
        gemm_body<128, 128, CPB_, 8>(arena, Th, B2t, zp, P2, NN_, KK_ * CHID_, y, 0);
    } else {
        const int g = y - CH2_;            // 0..7 -> (chunk 0..3, half 0..1)
        gemm_body<96, 192, CPB_, 7>(arena, Tx, B1t, zp, P1, NN_, KK_ * CIN_, g >> 1, g & 1);
    }
}

// ---------------------------------------------------------------------------
// Epilogue: one wave per node, lane = output channel. Sums bf16 split-K
// partials (L2-resident), mean-agg, root GEMV, GRU gates.
// ---------------------------------------------------------------------------
__global__ __launch_bounds__(256) void epilogue_kernel(
    const unsigned short* __restrict__ P1, const unsigned short* __restrict__ P2,
    const int* __restrict__ offs,
    const float* __restrict__ x, const float* __restrict__ hidden,
    const float* __restrict__ root_xr, const float* __restrict__ root_hr,
    const float* __restrict__ root_xz, const float* __restrict__ root_hz,
    const float* __restrict__ root_xn,
    const float* __restrict__ b_xr, const float* __restrict__ b_hr,
    const float* __restrict__ b_xz, const float* __restrict__ b_hz,
    const float* __restrict__ b_xn,
    float* __restrict__ out)
{
    __shared__ float xsh[4][32];
    __shared__ float hsh[4][64];
    const int w = threadIdx.x >> 6;
    const int o = threadIdx.x & 63;
    const int m = blockIdx.x * 4 + w;
    if (m >= NN_) return;

    if (o < 32) xsh[w][o] = x[(size_t)m * 32 + o];
    const float hval = hidden[(size_t)m * 64 + o];
    hsh[w][o] = hval;

    float axr = 0.f, axz = 0.f, axn = 0.f;
#pragma unroll
    for (int c = 0; c < CH1_; ++c) {
        const unsigned short* p = P1 + ((size_t)c * NN_ + m) * 192;
        axr += bf2f(p[o]); axz += bf2f(p[64 + o]); axn += bf2f(p[128 + o]);
    }
    float ahr = 0.f, ahz = 0.f;
#pragma unroll
    for (int c = 0; c < CH2_; ++c) {
        const unsigned short* p = P2 + ((size_t)c * NN_ + m) * 128;
        ahr += bf2f(p[o]); ahz += bf2f(p[64 + o]);
    }

    const int   dg   = offs[m + 1] - offs[m];
    const float dinv = 1.0f / fmaxf((float)dg, 1.0f);
    axr *= dinv; axz *= dinv; axn *= dinv; ahr *= dinv; ahz *= dinv;

    float sxr = 0.f, sxz = 0.f, sxn = 0.f;
#pragma unroll
    for (int c = 0; c < CIN_; ++c) {
        float xv = xsh[w][c];
        sxr += xv * root_xr[c * 64 + o];
        sxz += xv * root_xz[c * 64 + o];
        sxn += xv * root_xn[c * 64 + o];
    }
    float shr = 0.f, shz = 0.f;
#pragma unroll
    for (int c = 0; c < CHID_; ++c) {
        float hv = hsh[w][c];
        shr += hv * root_hr[c * 64 + o];
        shz += hv * root_hz[c * 64 + o];
    }

    const float conv_xr = axr + sxr + b_xr[o];
    const float conv_xz = axz + sxz + b_xz[o];
    const float conv_xn = axn + sxn + b_xn[o];
    const float hr_out  = ahr + shr + b_hr[o];
    const float conv_hz = ahz + shz + b_hz[o];

    const float rg = 1.0f / (1.0f + expf(-(conv_xr + hr_out)));
    const float zg = 1.0f / (1.0f + expf(-(conv_xz + conv_hz)));
    const float ng = tanhf(conv_xn + rg * hr_out);
    out[(size_t)m * 64 + o] = (1.0f - zg) * ng + zg * hval;
}

// ---------------------------------------------------------------------------
extern "C" void kernel_launch(void* const* d_in, const int* in_sizes, int n_in,
                              void* d_out, int out_size, void* d_ws, size_t ws_size,
                              hipStream_t stream)
{
    const float* x       = (const float*)d_in[0];
    const float* hidden  = (const float*)d_in[1];
    const int*   ei      = (const int*)  d_in[2];
    const float* attr    = (const float*)d_in[3];
    const float* W_xr    = (const float*)d_in[4];
    const float* root_xr = (const float*)d_in[5];
    const float* b_xr    = (const float*)d_in[6];
    const float* W_hr    = (const float*)d_in[7];
    const float* root_hr = (const float*)d_in[8];
    const float* b_hr    = (const float*)d_in[9];
    const float* W_xz    = (const float*)d_in[10];
    const float* root_xz = (const float*)d_in[11];
    const float* b_xz    = (const float*)d_in[12];
    const float* W_hz    = (const float*)d_in[13];
    const float* root_hz = (const float*)d_in[14];
    const float* b_hz    = (const float*)d_in[15];
    const float* W_xn    = (const float*)d_in[16];
    const float* root_xn = (const float*)d_in[17];
    const float* b_xn    = (const float*)d_in[18];
    // d_in[19..21] (W_hn/root_hn/b_hn) are dead: reference reuses hr_out.
    float* out = (float*)d_out;

    // Workspace (~175 MB). No aliasing (gemm-x reads Tx while gemm-h writes
    // P2 concurrently inside gemm_all). A/B staging may read a few rows past
    // a region's end -- all land in adjacent mapped workspace (finite bf16);
    // A K-tail loads zeros from zpad so those products are exactly 0.
    char* w = (char*)d_ws;
    unsigned short* Tx  = (unsigned short*)w; w += (size_t)NN_ * KK_ * CIN_  * 2;  // 48 MB
    unsigned short* Th  = (unsigned short*)w; w += (size_t)NN_ * KK_ * CHID_ * 2;  // 96 MB
    unsigned short* B1t = (unsigned short*)w; w += (size_t)192 * KK_ * CIN_  * 2;  // 1.5 MB
    unsigned short* B2t = (unsigned short*)w; w += (size_t)128 * KK_ * CHID_ * 2;  // 2.0 MB
    unsigned short* P1  = (unsigned short*)w; w += (size_t)CH1_ * NN_ * 192 * 2;   // 9.2 MB
    unsigned short* P2  = (unsigned short*)w; w += (size_t)CH2_ * NN_ * 128 * 2;   // 12.3 MB
    float4* meta_s = (float4*)w; w += (size_t)EE_ * 16;                            // 3.07 MB
    int* src_s  = (int*)w;   w += (size_t)EE_ * 4;                                 // 0.77 MB
    int* deg    = (int*)w;   w += (size_t)NN_ * 4;
    int* offs   = (int*)w;   w += (size_t)(NN_ + 4) * 4;
    int* cursor = (int*)w;   w += (size_t)NN_ * 4;
    unsigned short* zpad = (unsigned short*)w; w += 256;                           // zeroed

    const int MT = (NN_ + MTILE_ - 1) / MTILE_;   // 47 m-tiles

    hipMemsetAsync(deg, 0, (size_t)NN_ * 4, stream);
    hipMemsetAsync(zpad, 0, 256, stream);

    // ---- launch 1: deg count + tiled-transpose weight packs ----
    count_pack_kernel<<<CB_ + PACKB_, 256, 0, stream>>>(
        ei, deg, W_xr, W_xz, W_xn, W_hr, W_hz, B1t, B2t);

    // ---- scan + sorted edge records ----
    scan_kernel<<<1, 1024, 0, stream>>>(deg, offs, cursor);
    prep_kernel<<<(EE_ + 255) / 256, 256, 0, stream>>>(ei, attr, cursor, meta_s, src_s);

    // ---- T builds: MFMA formulation (v6, 256 threads) ----
    build_T_kernel<CHID_><<<NN_, 256, 0, stream>>>(meta_s, src_s, hidden, offs, Th);
    build_T_kernel<CIN_><<<NN_, 256, 0, stream>>>(meta_s, src_s, x, offs, Tx);

    // ---- merged x+h GEMMs (co-resident, one launch) ----
    gemm_all_kernel<<<dim3(MT, CH2_ + 2 * CH1_), 256, 0, stream>>>(
        Tx, B1t, P1, Th, B2t, P2, zpad);

    // ---- fused reduce + GRU epilogue (wave per node) ----
    epilogue_kernel<<<(NN_ + 3) / 4, 256, 0, stream>>>(
        P1, P2, offs, x, hidden,
        root_xr, root_hr, root_xz, root_hz, root_xn,
        b_xr, b_hr, b_xz, b_hz, b_xn, out);
}